// Round 1
// baseline (1119.465 us; speedup 1.0000x reference)
//
#include <hip/hip_runtime.h>
#include <hip/hip_fp16.h>

#define N_NODES 100000
#define N_FEATS 128
#define N_EDGES 3200000
#define N_HEADS 4
#define QK_HALFS ((size_t)N_NODES * 512)    // node-major: 512 halfs (4 heads x 128) per node
#define MAXD 128                            // max degree (Binomial mean 32, max ~60)
#define NBLK ((N_NODES + 255) / 256)        // 391 scan blocks
#define GROUPS 8
#define ROWS_PER_G (N_NODES / GROUPS)       // 12500
#define ERANGE (N_EDGES / GROUPS)           // 400000
#define STRIPS (N_NODES / 16)               // 6250 16-row strips (exact)
#define XCONV_BLKS 6250                     // 100000*128 halfs / 2048 per block
#define WCONV_BLKS 64                       // 2*4*128*128 / 2048
#define HIST_BLKS (N_EDGES / 256)           // 12500

typedef _Float16 half2t __attribute__((ext_vector_type(2)));
typedef _Float16 fp16x8 __attribute__((ext_vector_type(8)));
typedef float f32x4 __attribute__((ext_vector_type(4)));
struct alignas(16) H8 { half2t h[4]; };  // 8 halfs = 16B
union F4H8 { f32x4 f; H8 h; };

__device__ inline float fdot2(half2t a, half2t b, float c) {
#if __has_builtin(__builtin_amdgcn_fdot2)
  return __builtin_amdgcn_fdot2(a, b, c, false);
#else
  return c + (float)a.x * (float)b.x + (float)a.y * (float)b.y;
#endif
}

__device__ inline float dotH8(const H8& a, const H8& b, float c) {
  c = fdot2(a.h[0], b.h[0], c);
  c = fdot2(a.h[1], b.h[1], c);
  c = fdot2(a.h[2], b.h[2], c);
  c = fdot2(a.h[3], b.h[3], c);
  return c;
}

__device__ inline H8 cvt8(const float* p) {
  float4 f0 = *(const float4*)p;
  float4 f1 = *(const float4*)(p + 4);
  H8 h;
  h.h[0] = (half2t){(_Float16)f0.x, (_Float16)f0.y};
  h.h[1] = (half2t){(_Float16)f0.z, (_Float16)f0.w};
  h.h[2] = (half2t){(_Float16)f1.x, (_Float16)f1.y};
  h.h[3] = (half2t){(_Float16)f1.z, (_Float16)f1.w};
  return h;
}

// ---------------- FUSED: fp32->fp16 convert (x, W) + edge histogram ----------
// No LDS anywhere -> full occupancy for all block flavors.
__global__ __launch_bounds__(256) void convert_hist(const float* __restrict__ x,
                                                    const float* __restrict__ W,
                                                    _Float16* __restrict__ xh,
                                                    _Float16* __restrict__ wh,
                                                    const int* __restrict__ edges,
                                                    int* __restrict__ cnt) {
  int bid = blockIdx.x;
  if (bid < XCONV_BLKS) {
    size_t base = (size_t)bid * 2048 + threadIdx.x * 8;
    H8 h = cvt8(x + base);
    *(H8*)(xh + base) = h;
  } else if (bid < XCONV_BLKS + WCONV_BLKS) {
    size_t base = (size_t)(bid - XCONV_BLKS) * 2048 + threadIdx.x * 8;
    H8 h = cvt8(W + base);
    *(H8*)(wh + base) = h;
  } else {
    int e = (bid - XCONV_BLKS - WCONV_BLKS) * 256 + threadIdx.x;
    if (e < N_EDGES) atomicAdd(&cnt[edges[e]], 1);
  }
}

// ---------------- GEMM: qk = x @ W.T + b, LDS-free direct-fragment MFMA ------
// Wave = 16-row strip x 128-col tile. A and B fragments load straight from
// global fp16 (layout A[m=lane&15][k=quad*8+j] == row-major rows). No LDS, no
// barriers; 50000 waves hide latency. Consecutive blocks share a 32KB W-tile
// (L1/L2-hot). q/k written NODE-MAJOR: 512 halfs/node (head-major within node)
// so the fused attention pass gathers one contiguous 1KB row per edge.
__global__ __launch_bounds__(256) void gemm_qk2(const _Float16* __restrict__ xh,
                                                const _Float16* __restrict__ wh,
                                                const float* __restrict__ bias,
                                                __half* __restrict__ qh,
                                                __half* __restrict__ kh) {
  const int wid = blockIdx.x * 4 + (threadIdx.x >> 6);
  const int ct = wid / STRIPS;     // 0..7 col tile (consecutive wid -> same ct)
  const int strip = wid % STRIPS;
  const int m0 = strip * 16;       // always fully in-bounds (100000 = 6250*16)
  const int n0 = ct * 128;
  const int lane = threadIdx.x & 63;
  const int ml = lane & 15, quad = lane >> 4;
  const _Float16* xr = xh + (size_t)(m0 + ml) * 128 + quad * 8;
  const _Float16* wr = wh + (size_t)(n0 + ml) * 128 + quad * 8;
  f32x4 acc[8] = {};
#pragma unroll
  for (int kk = 0; kk < 4; kk++) {
    fp16x8 a = *(const fp16x8*)(xr + kk * 32);
#pragma unroll
    for (int t = 0; t < 8; t++) {
      fp16x8 b = *(const fp16x8*)(wr + (size_t)t * 2048 + kk * 32);
      acc[t] = __builtin_amdgcn_mfma_f32_16x16x32_f16(a, b, acc[t], 0, 0, 0);
    }
  }
#pragma unroll
  for (int t = 0; t < 8; t++) {
    int c = n0 + t * 16 + ml;       // 0..1023 output column
    float bv = bias[c];
    int h = c >> 8, f = c & 127;    // head 0..3, feature 0..127
    bool isk = (c >> 7) & 1;
    int within = h * 128 + f;       // 0..511 within the node's q or k row
#pragma unroll
    for (int r = 0; r < 4; r++) {
      int node = m0 + quad * 4 + r;
      __half v = __float2half(acc[t][r] + bv);
      size_t idx = (size_t)node * 512 + within;
      if (isk) kh[idx] = v;
      else __builtin_nontemporal_store(__half_as_short(v), (short*)&qh[idx]);
    }
  }
}

// ---------------- counting sort of edges by row ------------------------------
__global__ void zero_kernel(int* __restrict__ p, int n) {
  int i = blockIdx.x * 256 + threadIdx.x;
  if (i < n) p[i] = 0;
}

__global__ __launch_bounds__(256) void scan_partial(const int* __restrict__ cnt,
                                                    int* __restrict__ bsum) {
  __shared__ int ls[256];
  int t = threadIdx.x, b = blockIdx.x;
  int idx = b * 256 + t;
  ls[t] = (idx < N_NODES) ? cnt[idx] : 0;
  __syncthreads();
  for (int d = 128; d > 0; d >>= 1) {
    if (t < d) ls[t] += ls[t + d];
    __syncthreads();
  }
  if (t == 0) bsum[b] = ls[0];
}

__global__ __launch_bounds__(512) void scan_base(const int* __restrict__ bsum,
                                                 int* __restrict__ bbase,
                                                 int* __restrict__ off) {
  __shared__ int ls[512];
  int t = threadIdx.x;
  int v = (t < NBLK) ? bsum[t] : 0;
  ls[t] = v;
  __syncthreads();
  for (int d = 1; d < 512; d <<= 1) {
    int u = (t >= d) ? ls[t - d] : 0;
    __syncthreads();
    ls[t] += u;
    __syncthreads();
  }
  if (t < NBLK) bbase[t] = ls[t] - v;  // exclusive base
  if (t == 0) off[N_NODES] = N_EDGES;
}

__global__ __launch_bounds__(256) void scan_final(const int* __restrict__ cnt,
                                                  const int* __restrict__ bbase,
                                                  int* __restrict__ off,
                                                  int* __restrict__ cursor) {
  __shared__ int ls[256];
  int t = threadIdx.x, b = blockIdx.x;
  int idx = b * 256 + t;
  int v = (idx < N_NODES) ? cnt[idx] : 0;
  ls[t] = v;
  __syncthreads();
  for (int d = 1; d < 256; d <<= 1) {
    int u = (t >= d) ? ls[t - d] : 0;
    __syncthreads();
    ls[t] += u;
    __syncthreads();
  }
  if (idx < N_NODES) {
    int ex = bbase[b] + ls[t] - v;
    off[idx] = ex;
    cursor[idx] = ex;
  }
}

// XCD-steered scatter: group g = blockIdx&7 owns rows [g*12500,(g+1)*12500),
// scans ALL edges (L3-resident), acts only on owned rows -> a node's sce lines
// are written from one XCD within a short window (line merging).
__global__ __launch_bounds__(256) void scatter_v2(const int* __restrict__ edges,
                                                  int* __restrict__ cursor,
                                                  int2* __restrict__ sce) {
  const int g = blockIdx.x & 7;
  const int sub = blockIdx.x >> 3;
  const int nsub = gridDim.x >> 3;
  const int rlo = g * ROWS_PER_G, rhi = rlo + ROWS_PER_G;
  for (int base = sub * 256; base < N_EDGES; base += nsub * 256) {
    int e = base + threadIdx.x;
    int r = edges[e];
    if (r >= rlo && r < rhi) {
      int p = atomicAdd(&cursor[r], 1);
      sce[p] = make_int2(edges[N_EDGES + e], e);
    }
  }
}

// ---------------- per-node softmax attention, ALL 4 HEADS in one pass --------
// Each edge gathers one contiguous 1KB k-row (4 coalesced 256B segments across
// a 16-lane group); lane l holds head-j fragment kr[j*16+l], which is the
// identical per-lane dot assignment as the old per-pair passes (numerics
// preserved). Final combine replicates the old two-pass accumulation order.
__global__ __launch_bounds__(256) void attn_fused(const __half* __restrict__ qp,
                                                  const __half* __restrict__ kp,
                                                  const int* __restrict__ off,
                                                  const int2* __restrict__ sce,
                                                  float* __restrict__ att) {
  __shared__ float4 sc[4][MAXD];
  const int wave = threadIdx.x >> 6;
  const int lane = threadIdx.x & 63;
  const int g = lane >> 4, l = lane & 15;
  const int n = blockIdx.x * 4 + wave;
  if (n >= N_NODES) return;
  const int start = off[n];
  const int deg = off[n + 1] - start;
  if (deg <= 0) return;
  const int dmin = deg < MAXD ? deg : MAXD;

  H8 qv[4];
  {
    const f32x4* qr = (const f32x4*)(qp + (size_t)n * 512);
#pragma unroll
    for (int j = 0; j < 4; j++) {
      F4H8 u;
      u.f = __builtin_nontemporal_load(qr + j * 16 + l);
      qv[j] = u.h;
    }
  }

  for (int i0 = 0; i0 < dmin; i0 += 8) {
    int col[2]; bool act[2]; int ii[2];
#pragma unroll
    for (int u = 0; u < 2; u++) {
      ii[u] = i0 + u * 4 + g;
      act[u] = ii[u] < dmin;
      col[u] = sce[start + (act[u] ? ii[u] : 0)].x;
    }
    H8 kv[2][4];
#pragma unroll
    for (int u = 0; u < 2; u++) {
      const H8* kr = (const H8*)(kp + (size_t)col[u] * 512);
#pragma unroll
      for (int j = 0; j < 4; j++) kv[u][j] = kr[j * 16 + l];
    }
    float a[2][4];
#pragma unroll
    for (int u = 0; u < 2; u++)
#pragma unroll
      for (int j = 0; j < 4; j++) a[u][j] = dotH8(kv[u][j], qv[j], 0.f);
#pragma unroll
    for (int u = 0; u < 2; u++)
#pragma unroll
      for (int o = 1; o < 16; o <<= 1) {
        a[u][0] += __shfl_xor(a[u][0], o);
        a[u][1] += __shfl_xor(a[u][1], o);
        a[u][2] += __shfl_xor(a[u][2], o);
        a[u][3] += __shfl_xor(a[u][3], o);
      }
#pragma unroll
    for (int u = 0; u < 2; u++)
      if (l == 0 && act[u])
        sc[wave][ii[u]] = make_float4(a[u][0], a[u][1], a[u][2], a[u][3]);
  }
  __threadfence_block();  // wave-private LDS region: order writes before reads

  float mx0 = -1e30f, mx1 = -1e30f, mx2 = -1e30f, mx3 = -1e30f;
  for (int i = lane; i < dmin; i += 64) {
    float4 v = sc[wave][i];
    mx0 = fmaxf(mx0, v.x); mx1 = fmaxf(mx1, v.y);
    mx2 = fmaxf(mx2, v.z); mx3 = fmaxf(mx3, v.w);
  }
#pragma unroll
  for (int o = 32; o > 0; o >>= 1) {
    mx0 = fmaxf(mx0, __shfl_xor(mx0, o));
    mx1 = fmaxf(mx1, __shfl_xor(mx1, o));
    mx2 = fmaxf(mx2, __shfl_xor(mx2, o));
    mx3 = fmaxf(mx3, __shfl_xor(mx3, o));
  }
  float sm0 = 0.f, sm1 = 0.f, sm2 = 0.f, sm3 = 0.f;
  for (int i = lane; i < dmin; i += 64) {
    float4 v = sc[wave][i];
    float4 e;
    e.x = __expf(v.x - mx0); e.y = __expf(v.y - mx1);
    e.z = __expf(v.z - mx2); e.w = __expf(v.w - mx3);
    sc[wave][i] = e;  // cache exps; only this lane reads index i back
    sm0 += e.x; sm1 += e.y; sm2 += e.z; sm3 += e.w;
  }
#pragma unroll
  for (int o = 32; o > 0; o >>= 1) {
    sm0 += __shfl_xor(sm0, o);
    sm1 += __shfl_xor(sm1, o);
    sm2 += __shfl_xor(sm2, o);
    sm3 += __shfl_xor(sm3, o);
  }
  float rs0 = 1.f / sm0, rs1 = 1.f / sm1, rs2 = 1.f / sm2, rs3 = 1.f / sm3;
  for (int i = lane; i < dmin; i += 64) {
    float4 e = sc[wave][i];
    // replicate old two-pass accumulation order exactly:
    // pass1 wrote 0.25*(e0*rs0+e1*rs1); pass2 added 0.25*(e2*rs2+e3*rs3)
    float w = 0.25f * (e.x * rs0 + e.y * rs1) + 0.25f * (e.z * rs2 + e.w * rs3);
    att[start + i] = w;  // coalesced; stays L2/L3-warm for permute
  }
}

// XCD-steered permute: group g owns eid range; scans all slots, writes only
// owned eids -> out lines merged within one XCD's L2.
__global__ __launch_bounds__(256) void permute_v2(const int2* __restrict__ sce,
                                                  const float* __restrict__ att,
                                                  float* __restrict__ out) {
  const int g = blockIdx.x & 7;
  const int sub = blockIdx.x >> 3;
  const int nsub = gridDim.x >> 3;
  const int elo = g * ERANGE, ehi = elo + ERANGE;
  for (int base = sub * 256; base < N_EDGES; base += nsub * 256) {
    int p = base + threadIdx.x;
    int eid = sce[p].y;
    if (eid >= elo && eid < ehi) out[eid] = att[p];
  }
}

extern "C" void kernel_launch(void* const* d_in, const int* in_sizes, int n_in,
                              void* d_out, int out_size, void* d_ws, size_t ws_size,
                              hipStream_t stream) {
  const float* x = (const float*)d_in[0];
  const float* W = (const float*)d_in[1];
  const float* b = (const float*)d_in[2];
  const int* edges = (const int*)d_in[3];
  float* out = (float*)d_out;

  char* ws = (char*)d_ws;
  size_t o = 0;
  __half* qh = (__half*)(ws + o); o += QK_HALFS * 2;          // 102.4 MB (node-major)
  __half* kh = (__half*)(ws + o); o += QK_HALFS * 2;          // 102.4 MB
  int* cnt    = (int*)(ws + o); o += (size_t)N_NODES * 4;
  int* off    = (int*)(ws + o); o += (size_t)(N_NODES + 16) * 4;
  int* cursor = (int*)(ws + o); o += (size_t)N_NODES * 4;
  int* bsum   = (int*)(ws + o); o += (size_t)512 * 4;
  int* bbase  = (int*)(ws + o); o += (size_t)512 * 4;
  int2* sce   = (int2*)(ws + o); o += (size_t)N_EDGES * 8;    // 25.6 MB (col,eid)
  float* att  = (float*)(ws + o); o += (size_t)N_EDGES * 4;   // 12.8 MB
  _Float16* wh = (_Float16*)(ws + o); o += (size_t)2 * N_HEADS * 128 * 128 * 2; // 512 KB
  // xh (25.6 MB) ALIASES sce: gemm_qk2's last read of xh precedes scatter_v2's
  // first write of sce in stream order.
  _Float16* xh = (_Float16*)sce;
  (void)ws_size; (void)in_sizes; (void)n_in; (void)out_size;  // ~245 MB total

  zero_kernel<<<dim3((N_NODES + 255) / 256), dim3(256), 0, stream>>>(cnt, N_NODES);
  convert_hist<<<dim3(XCONV_BLKS + WCONV_BLKS + HIST_BLKS), dim3(256), 0, stream>>>(
      x, W, xh, wh, edges, cnt);
  gemm_qk2<<<dim3(STRIPS * 8 / 4), dim3(256), 0, stream>>>(xh, wh, b, qh, kh);
  scan_partial<<<dim3(NBLK), dim3(256), 0, stream>>>(cnt, bsum);
  scan_base<<<dim3(1), dim3(512), 0, stream>>>(bsum, bbase, off);
  scan_final<<<dim3(NBLK), dim3(256), 0, stream>>>(cnt, bbase, off, cursor);
  scatter_v2<<<dim3(4096), dim3(256), 0, stream>>>(edges, cursor, sce);
  attn_fused<<<dim3((N_NODES + 3) / 4), dim3(256), 0, stream>>>(
      qh, kh, off, sce, att);
  permute_v2<<<dim3(4096), dim3(256), 0, stream>>>(sce, att, out);
}